// Round 6
// baseline (219.492 us; speedup 1.0000x reference)
//
#include <hip/hip_runtime.h>
#include <hip/hip_bf16.h>

// Problem constants (B=2, S=2048, H=768, NH=12, HS=64)
#define BATCH 2
#define SEQ   2048
#define HID   768
#define NH    12
#define HS    64
#define MROWS (BATCH*SEQ)   // 4096
#define N3    (3*HID)       // 2304
#define HB    (NH*BATCH)    // 24

typedef __attribute__((ext_vector_type(8))) short short8;
typedef __attribute__((ext_vector_type(4))) float floatx4;

// logits in log2 domain: Q pre-scaled by 0.125*log2(e) in GEMM epilogue
#define QSCALE 0.1803368801111204f

__device__ __forceinline__ unsigned short f2bf(float x){
  __hip_bfloat16 h = __float2bfloat16(x);
  return __builtin_bit_cast(unsigned short, h);
}
__device__ __forceinline__ unsigned int f2bf2(float lo, float hi){
  return (unsigned int)f2bf(lo) | ((unsigned int)f2bf(hi) << 16);
}
// async global->LDS, 16B per lane. LDS dest must be wave-uniform base + lane*16.
__device__ __forceinline__ void glds16(const unsigned short* g, unsigned short* l){
  __builtin_amdgcn_global_load_lds(
    (const __attribute__((address_space(1))) unsigned int*)g,
    (__attribute__((address_space(3))) unsigned int*)l, 16, 0, 0);
}

// ---------- convert X/Wq/Wk/Wv to bf16 + mask precompute, ONE launch ----------
__global__ void f2bf_all_kernel(const float* __restrict__ X,
                                const float* __restrict__ Wq,
                                const float* __restrict__ Wk,
                                const float* __restrict__ Wv,
                                const int* __restrict__ mask,
                                unsigned short* __restrict__ Xb,
                                unsigned short* __restrict__ Wb,
                                float* __restrict__ maskaddG,
                                int* __restrict__ flagsG){
  const int XQ = MROWS*HID/4;   // float4 quads in X
  const int WQ = HID*HID/4;     // per weight
  const int NB = (XQ + 3*WQ)/256;
  const int tid = threadIdx.x;
  if(blockIdx.x == NB){
    for(int i=tid;i<BATCH*SEQ;i+=256) maskaddG[i] = mask[i] ? 0.f : -1e30f;
    if(tid < BATCH*32){
      int b = tid >> 5, t = tid & 31;
      const int* mrow = mask + b*SEQ + t*64;
      int any = 0;
      for(int i=0;i<64;i++) any |= (mrow[i]==0);
      flagsG[tid] = any;
    }
    return;
  }
  int i = blockIdx.x * 256 + tid;
  const float* src; unsigned short* dst; int off;
  if(i < XQ){ src = X; dst = Xb; off = i; }
  else {
    int j = i - XQ;
    int w = j / WQ; off = j - w*WQ;
    src = (w==0) ? Wq : (w==1) ? Wk : Wv;
    dst = Wb + (size_t)w*HID*HID;
  }
  float4 v = reinterpret_cast<const float4*>(src)[off];
  ushort4 o;
  o.x = f2bf(v.x); o.y = f2bf(v.y); o.z = f2bf(v.z); o.w = f2bf(v.w);
  reinterpret_cast<ushort4*>(dst)[off] = o;
}

// ---------- fused QKV projection GEMM ----------
// 128x128 tile, BK=32, double-buffered async LDS staging, swizzled layout.
// Q/K epilogue: LDS bounce -> coalesced 16B stores. V -> Vtb [hb][64][s].
__global__ __launch_bounds__(256) void qkv_gemm_kernel(
    const unsigned short* __restrict__ Xb,   // [4096][768]
    const unsigned short* __restrict__ Wb,   // [2304][768]
    const float* __restrict__ bq, const float* __restrict__ bk, const float* __restrict__ bv,
    unsigned short* __restrict__ Qb, unsigned short* __restrict__ Kb,
    unsigned short* __restrict__ Vtb)
{
  __shared__ __align__(16) union {
    struct { unsigned short A[2][128][32]; unsigned short B[2][128][32]; } s; // 32 KB
    unsigned short T[4][64][72];                                             // 36 KB (epilogue)
  } u;
  const int m0 = blockIdx.y << 7;
  const int n0 = blockIdx.x << 7;
  const int tid  = threadIdx.x;
  const int wave = tid >> 6, lane = tid & 63;
  const int wr = wave >> 1, wc = wave & 1;
  const int quad = lane >> 4, l15 = lane & 15;

  const unsigned short* gsrc[4];
  unsigned short* ldst[4];
  #pragma unroll
  for(int p=0;p<4;p++){
    int ck  = ((p&1)<<8) + tid;            // 0..511
    int row = ck>>2, c = ck&3, pc = c ^ (row&3);
    if(p<2){ gsrc[p] = Xb + (size_t)(m0+row)*HID + (pc<<3); ldst[p] = &u.s.A[0][row][c<<3]; }
    else   { gsrc[p] = Wb + (size_t)(n0+row)*HID + (pc<<3); ldst[p] = &u.s.B[0][row][c<<3]; }
  }

  floatx4 acc[4][4];
  #pragma unroll
  for(int i=0;i<4;i++)
    #pragma unroll
    for(int j=0;j<4;j++) acc[i][j] = (floatx4){0.f,0.f,0.f,0.f};

  auto stage = [&](int buf, int k0){
    const int bo = buf*(128*32);
    #pragma unroll
    for(int p=0;p<4;p++) glds16(gsrc[p] + k0, ldst[p] + bo);
  };

  stage(0, 0);
  __syncthreads();

  const int swa = l15 & 3;
  for(int t=0;t<HID/32;t++){
    const int buf = t & 1;
    if(t < HID/32 - 1) stage(buf^1, (t+1)*32);
    short8 a[4], b[4];
    #pragma unroll
    for(int i=0;i<4;i++)
      a[i] = *reinterpret_cast<const short8*>(&u.s.A[buf][wr*64+i*16+l15][(quad^swa)<<3]);
    #pragma unroll
    for(int j=0;j<4;j++)
      b[j] = *reinterpret_cast<const short8*>(&u.s.B[buf][wc*64+j*16+l15][(quad^swa)<<3]);
    #pragma unroll
    for(int i=0;i<4;i++)
      #pragma unroll
      for(int j=0;j<4;j++)
        acc[i][j] = __builtin_amdgcn_mfma_f32_16x16x32_bf16(a[i], b[j], acc[i][j], 0, 0, 0);
    __syncthreads();
  }

  // ---- epilogue; C layout col=lane&15 (n), row=quad*4+reg (m) ----
  const int which = n0 / HID;
  const int nbase = n0 - which*HID + wc*64;
  const int head  = nbase >> 6;
  const int b_    = m0 >> 11;
  const int hb    = head*BATCH + b_;
  const int s0    = (m0 & 2047) + wr*64;
  if(which < 2){
    unsigned short* dst = which==0 ? Qb : Kb;
    const float* bias = which==0 ? bq : bk;
    const float scale = which==0 ? QSCALE : 1.0f;
    #pragma unroll
    for(int j=0;j<4;j++){
      const float bb = bias[nbase + j*16 + l15];
      #pragma unroll
      for(int i=0;i<4;i++)
        #pragma unroll
        for(int r=0;r<4;r++)
          u.T[wave][i*16 + quad*4 + r][j*16 + l15] = f2bf((acc[i][j][r] + bb)*scale);
    }
    #pragma unroll
    for(int p=0;p<8;p++){
      const int row = p*8 + (lane>>3), dc = (lane&7)*8;
      uint4 v = *reinterpret_cast<const uint4*>(&u.T[wave][row][dc]);
      *reinterpret_cast<uint4*>(dst + ((size_t)(hb<<11) + s0 + row)*HS + dc) = v;
    }
  } else {
    #pragma unroll
    for(int j=0;j<4;j++){
      const float bb = bv[nbase + j*16 + l15];
      #pragma unroll
      for(int i=0;i<4;i++){
        uint2 pk;
        pk.x = f2bf2(acc[i][j][0]+bb, acc[i][j][1]+bb);
        pk.y = f2bf2(acc[i][j][2]+bb, acc[i][j][3]+bb);
        *reinterpret_cast<uint2*>(&u.T[wave][j*16+l15][i*16 + quad*4]) = pk;  // T[d][m]
      }
    }
    #pragma unroll
    for(int p=0;p<8;p++){
      const int d = p*8 + (lane>>3), cm = lane & 7;
      uint4 v = *reinterpret_cast<const uint4*>(&u.T[wave][d][cm*8]);
      *reinterpret_cast<uint4*>(Vtb + ((size_t)(hb*HS) + d)*SEQ + s0 + cm*8) = v;
    }
  }
}

// ---------- flash attention, no-max softmax, S^T, optional split-K ----------
// nsplit=2: grid HB*32*2; each block does 16 K-tiles; half0 -> out (fp32,
// unnormalized) + l0, half1 -> O1 + l1. nsplit=1: grid HB*32, final output.
// K double-buffered async in LDS; V in registers (issued before S-phase);
// P packed -> Ps stride 68 (b64 ops, <=4-way banks).
__global__ __launch_bounds__(256, 4) void attn_kernel(
    const unsigned short* __restrict__ Qb,   // [hb][2048][64] (pre-scaled, log2 domain)
    const unsigned short* __restrict__ Kb,   // [hb][2048][64]
    const unsigned short* __restrict__ Vtb,  // [hb][64][2048]
    const float* __restrict__ maskaddG,      // [B][2048]
    const int* __restrict__ flagsG,          // [B][32]
    float* __restrict__ out,                 // final or O0 partial
    float* __restrict__ O1,                  // partial half 1
    float* __restrict__ l0, float* __restrict__ l1,
    int nsplit)
{
  __shared__ __align__(16) unsigned short Ks2[2][64][64];   // 16 KB
  __shared__ __align__(16) unsigned short Ps2[4][16][68];   // 8.5 KB

  const int bid = blockIdx.x;
  const int tid = threadIdx.x, wave = tid >> 6, lane = tid & 63;
  const int quad = lane >> 4, l15 = lane & 15;
  int hb, qt, half, t0, tn;
  if(nsplit == 2){ hb = bid >> 6; int rem = bid & 63; qt = rem >> 1; half = rem & 1; t0 = half << 4; tn = 16; }
  else           { hb = bid >> 5; qt = bid & 31; half = 0; t0 = 0; tn = 32; }
  const int q0 = qt << 6;
  const int b_ = hb & 1, head = hb >> 1;

  // K staging descriptors (chunk = p*256+tid; row=ck/8, c=ck%8, swizzle c^(row&7))
  const unsigned short* gK[2]; unsigned short* lK[2];
  #pragma unroll
  for(int p=0;p<2;p++){
    int ck = (p<<8) + tid;
    int row = ck>>3, c = ck&7, pc = c ^ (row&7);
    gK[p] = Kb + ((size_t)(hb<<11) + row)*HS + (pc<<3);
    lK[p] = &Ks2[0][row][c<<3];
  }
  auto stageK = [&](int buf, int t){
    const int bo = buf*(64*64);
    #pragma unroll
    for(int p=0;p<2;p++) glds16(gK[p] + (size_t)(t<<6)*HS, lK[p] + bo);
  };

  stageK(0, t0);                             // async prefetch first tile

  // Q fragments: direct b128 loads (scale folded in by GEMM)
  short8 a_q[2];
  {
    const unsigned short* qsrc = Qb + ((size_t)(hb<<11) + q0 + wave*16 + l15)*HS;
    a_q[0] = *reinterpret_cast<const short8*>(qsrc + quad*8);
    a_q[1] = *reinterpret_cast<const short8*>(qsrc + 32 + quad*8);
  }

  float lsum4[4] = {0.f,0.f,0.f,0.f};
  floatx4 o_acc[4];
  #pragma unroll
  for(int dt=0;dt<4;dt++) o_acc[dt] = (floatx4){0.f,0.f,0.f,0.f};

  const unsigned short* vbase = Vtb + (size_t)(hb*HS)*SEQ;

  __syncthreads();                           // first tile staged

  const int sw = l15 & 7;
  for(int i=0;i<tn;i++){
    const int t = t0 + i, buf = i & 1, k0 = t << 6;
    if(i < tn-1) stageK(buf^1, t+1);         // async prefetch next K tile

    // V fragments: registers, issued early so S-phase hides the latency
    short8 vf[4][2];
    #pragma unroll
    for(int dt=0;dt<4;dt++)
      #pragma unroll
      for(int c=0;c<2;c++)
        vf[dt][c] = *reinterpret_cast<const short8*>(
            vbase + (size_t)(dt*16 + l15)*SEQ + k0 + c*32 + quad*8);

    const unsigned short (*Kst)[64] = Ks2[buf];

    // S^T: rows = keys (quad*4+r), cols = queries (l15)
    floatx4 st[4];
    #pragma unroll
    for(int kt=0;kt<4;kt++){
      st[kt] = (floatx4){0.f,0.f,0.f,0.f};
      #pragma unroll
      for(int c=0;c<2;c++){
        short8 kf = *reinterpret_cast<const short8*>(
            &Kst[kt*16 + l15][(((c<<2)+quad)^sw)<<3]);
        st[kt] = __builtin_amdgcn_mfma_f32_16x16x32_bf16(kf, a_q[c], st[kt], 0, 0, 0);
      }
    }

    // P = exp2(S [+ mask]); pack pairs; write P[q=l15][key] (2x b64)
    const bool masked = (flagsG[(b_<<5) + t] != 0);   // wave-uniform
    #pragma unroll
    for(int kt=0;kt<4;kt++){
      float p0,p1,p2,p3;
      if(!masked){
        p0 = exp2f(st[kt][0]); p1 = exp2f(st[kt][1]);
        p2 = exp2f(st[kt][2]); p3 = exp2f(st[kt][3]);
      } else {
        float4 ma = *reinterpret_cast<const float4*>(
            maskaddG + (b_<<11) + k0 + kt*16 + quad*4);
        p0 = exp2f(st[kt][0] + ma.x); p1 = exp2f(st[kt][1] + ma.y);
        p2 = exp2f(st[kt][2] + ma.z); p3 = exp2f(st[kt][3] + ma.w);
      }
      lsum4[0] += p0; lsum4[1] += p1; lsum4[2] += p2; lsum4[3] += p3;
      uint2 pk;
      pk.x = f2bf2(p0, p1);
      pk.y = f2bf2(p2, p3);
      *reinterpret_cast<uint2*>(&Ps2[wave][l15][kt*16 + quad*4]) = pk;
    }

    // A-frag read (same-wave RAW via lgkmcnt): 4x b64 -> two short8
    short8 ap0, ap1;
    {
      unsigned long long x0 = *reinterpret_cast<const unsigned long long*>(&Ps2[wave][l15][quad*8]);
      unsigned long long x1 = *reinterpret_cast<const unsigned long long*>(&Ps2[wave][l15][quad*8 + 4]);
      unsigned long long y0 = *reinterpret_cast<const unsigned long long*>(&Ps2[wave][l15][32 + quad*8]);
      unsigned long long y1 = *reinterpret_cast<const unsigned long long*>(&Ps2[wave][l15][32 + quad*8 + 4]);
      union { unsigned long long u[2]; short8 s; } cv0, cv1;
      cv0.u[0] = x0; cv0.u[1] = x1;
      cv1.u[0] = y0; cv1.u[1] = y1;
      ap0 = cv0.s; ap1 = cv1.s;
    }
    #pragma unroll
    for(int dt=0;dt<4;dt++){
      o_acc[dt] = __builtin_amdgcn_mfma_f32_16x16x32_bf16(ap0, vf[dt][0], o_acc[dt], 0, 0, 0);
      o_acc[dt] = __builtin_amdgcn_mfma_f32_16x16x32_bf16(ap1, vf[dt][1], o_acc[dt], 0, 0, 0);
    }
    __syncthreads();   // staged K(t+1) drained; everyone done reading Ks2[buf]
  }

  // per-query row sum: lane holds q=l15 partial; reduce across quads
  float lsum = (lsum4[0]+lsum4[1]) + (lsum4[2]+lsum4[3]);
  lsum += __shfl_xor(lsum, 16);
  lsum += __shfl_xor(lsum, 32);

  if(nsplit == 2){
    float* Op = half ? O1 : out;
    float* lp = half ? l1 : l0;
    if(lane < 16) lp[(hb<<11) + q0 + wave*16 + l15] = lsum;
    #pragma unroll
    for(int dt=0;dt<4;dt++)
      #pragma unroll
      for(int r=0;r<4;r++){
        const int srow = q0 + wave*16 + quad*4 + r;
        Op[((size_t)(b_<<11) + srow)*HID + (head<<6) + dt*16 + l15] = o_acc[dt][r];
      }
  } else {
    float linv[4];
    #pragma unroll
    for(int r=0;r<4;r++) linv[r] = 1.0f / __shfl(lsum, quad*4 + r);
    #pragma unroll
    for(int dt=0;dt<4;dt++)
      #pragma unroll
      for(int r=0;r<4;r++){
        const int srow = q0 + wave*16 + quad*4 + r;
        out[((size_t)(b_<<11) + srow)*HID + (head<<6) + dt*16 + l15] =
          o_acc[dt][r] * linv[r];
      }
  }
}

// ---------- split-K combine: out = (out + O1) / (l0 + l1) ----------
__global__ void combine_kernel(float* __restrict__ out,
                               const float* __restrict__ O1,
                               const float* __restrict__ l0,
                               const float* __restrict__ l1){
  int i4 = blockIdx.x*256 + threadIdx.x;     // MROWS*HID/4 threads
  int i = i4 << 2;
  int b = (i >= SEQ*HID) ? 1 : 0;
  int rem = i - b*SEQ*HID;
  int s = rem / HID;
  int h = rem - s*HID;
  int hb = (h >> 6)*BATCH + b;
  float l = l0[(hb<<11) + s] + l1[(hb<<11) + s];
  float inv = 1.0f / l;
  float4 a = reinterpret_cast<const float4*>(out)[i4];
  float4 c = reinterpret_cast<const float4*>(O1)[i4];
  float4 r;
  r.x = (a.x + c.x)*inv; r.y = (a.y + c.y)*inv;
  r.z = (a.z + c.z)*inv; r.w = (a.w + c.w)*inv;
  reinterpret_cast<float4*>(out)[i4] = r;
}

extern "C" void kernel_launch(void* const* d_in, const int* in_sizes, int n_in,
                              void* d_out, int out_size, void* d_ws, size_t ws_size,
                              hipStream_t stream) {
  const float* X    = (const float*)d_in[0];
  const int*   mask = (const int*)  d_in[1];
  const float* Wq   = (const float*)d_in[2];
  const float* bq   = (const float*)d_in[3];
  const float* Wk   = (const float*)d_in[4];
  const float* bk   = (const float*)d_in[5];
  const float* Wv   = (const float*)d_in[6];
  const float* bv   = (const float*)d_in[7];
  float* out = (float*)d_out;

  char* ws = (char*)d_ws;
  unsigned short* Xb  = (unsigned short*)ws;                 // 6,291,456 B
  unsigned short* Wb  = Xb  + (size_t)MROWS*HID;             // 3,538,944 B
  unsigned short* Qb  = Wb  + (size_t)N3*HID;                // 6,291,456 B
  unsigned short* Kb  = Qb  + (size_t)HB*SEQ*HS;
  unsigned short* Vtb = Kb  + (size_t)HB*SEQ*HS;
  float* maskaddG = (float*)(Vtb + (size_t)HB*SEQ*HS);       // 16,384 B
  int*   flagsG   = (int*)(maskaddG + MROWS);                // 256 B
  float* l0       = (float*)((char*)flagsG + 256);           // 196,608 B
  float* l1       = l0 + (size_t)HB*SEQ;                     // 196,608 B
  float* O1       = l1 + (size_t)HB*SEQ;                     // 12,582,912 B
  const size_t ws_needed_split = ((char*)(O1 + (size_t)MROWS*HID)) - ws;
  const bool do_split = (ws_size >= ws_needed_split);

  const int total_quads = (MROWS*HID + 3*HID*HID)/4;
  f2bf_all_kernel<<<total_quads/256 + 1, 256, 0, stream>>>(
      X, Wq, Wk, Wv, mask, Xb, Wb, maskaddG, flagsG);

  qkv_gemm_kernel<<<dim3(N3/128, MROWS/128), 256, 0, stream>>>(
      Xb, Wb, bq, bk, bv, Qb, Kb, Vtb);

  if(do_split){
    attn_kernel<<<HB*32*2, 256, 0, stream>>>(
        Qb, Kb, Vtb, maskaddG, flagsG, out, O1, l0, l1, 2);
    combine_kernel<<<MROWS*HID/4/256, 256, 0, stream>>>(out, O1, l0, l1);
  } else {
    attn_kernel<<<HB*32, 256, 0, stream>>>(
        Qb, Kb, Vtb, maskaddG, flagsG, out, out, out, out, 1);
  }
}

// Round 7
// 175.153 us; speedup vs baseline: 1.2531x; 1.2531x over previous
//
#include <hip/hip_runtime.h>
#include <hip/hip_bf16.h>

// Problem constants (B=2, S=2048, H=768, NH=12, HS=64)
#define BATCH 2
#define SEQ   2048
#define HID   768
#define NH    12
#define HS    64
#define MROWS (BATCH*SEQ)   // 4096
#define N3    (3*HID)       // 2304
#define HB    (NH*BATCH)    // 24

typedef __attribute__((ext_vector_type(8))) short short8;
typedef __attribute__((ext_vector_type(4))) float floatx4;

// logits in log2 domain: Q pre-scaled by 0.125*log2(e) in GEMM epilogue
#define QSCALE 0.1803368801111204f

__device__ __forceinline__ unsigned short f2bf(float x){
  __hip_bfloat16 h = __float2bfloat16(x);
  return __builtin_bit_cast(unsigned short, h);
}
__device__ __forceinline__ unsigned int f2bf2(float lo, float hi){
  return (unsigned int)f2bf(lo) | ((unsigned int)f2bf(hi) << 16);
}
// async global->LDS, 16B per lane. LDS dest must be wave-uniform base + lane*16.
__device__ __forceinline__ void glds16(const unsigned short* g, unsigned short* l){
  __builtin_amdgcn_global_load_lds(
    (const __attribute__((address_space(1))) unsigned int*)g,
    (__attribute__((address_space(3))) unsigned int*)l, 16, 0, 0);
}

// ---------- convert X/Wq/Wk/Wv to bf16 + mask precompute, ONE launch ----------
__global__ void f2bf_all_kernel(const float* __restrict__ X,
                                const float* __restrict__ Wq,
                                const float* __restrict__ Wk,
                                const float* __restrict__ Wv,
                                const int* __restrict__ mask,
                                unsigned short* __restrict__ Xb,
                                unsigned short* __restrict__ Wb,
                                float* __restrict__ maskaddG,
                                int* __restrict__ flagsG){
  const int XQ = MROWS*HID/4;   // float4 quads in X
  const int WQ = HID*HID/4;     // per weight
  const int NB = (XQ + 3*WQ)/256;
  const int tid = threadIdx.x;
  if(blockIdx.x == NB){
    for(int i=tid;i<BATCH*SEQ;i+=256) maskaddG[i] = mask[i] ? 0.f : -1e30f;
    if(tid < BATCH*32){
      int b = tid >> 5, t = tid & 31;
      const int* mrow = mask + b*SEQ + t*64;
      int any = 0;
      for(int i=0;i<64;i++) any |= (mrow[i]==0);
      flagsG[tid] = any;
    }
    return;
  }
  int i = blockIdx.x * 256 + tid;
  const float* src; unsigned short* dst; int off;
  if(i < XQ){ src = X; dst = Xb; off = i; }
  else {
    int j = i - XQ;
    int w = j / WQ; off = j - w*WQ;
    src = (w==0) ? Wq : (w==1) ? Wk : Wv;
    dst = Wb + (size_t)w*HID*HID;
  }
  float4 v = reinterpret_cast<const float4*>(src)[off];
  ushort4 o;
  o.x = f2bf(v.x); o.y = f2bf(v.y); o.z = f2bf(v.z); o.w = f2bf(v.w);
  reinterpret_cast<ushort4*>(dst)[off] = o;
}

// ---------- fused QKV projection GEMM ----------
// 128x128 tile, BK=32, double-buffered async LDS staging, swizzled layout.
// Q/K epilogue: LDS bounce -> coalesced 16B stores. V -> Vtb [hb][64][s].
__global__ __launch_bounds__(256) void qkv_gemm_kernel(
    const unsigned short* __restrict__ Xb,   // [4096][768]
    const unsigned short* __restrict__ Wb,   // [2304][768]
    const float* __restrict__ bq, const float* __restrict__ bk, const float* __restrict__ bv,
    unsigned short* __restrict__ Qb, unsigned short* __restrict__ Kb,
    unsigned short* __restrict__ Vtb)
{
  __shared__ __align__(16) union {
    struct { unsigned short A[2][128][32]; unsigned short B[2][128][32]; } s; // 32 KB
    unsigned short T[4][64][72];                                             // 36 KB (epilogue)
  } u;
  const int m0 = blockIdx.y << 7;
  const int n0 = blockIdx.x << 7;
  const int tid  = threadIdx.x;
  const int wave = tid >> 6, lane = tid & 63;
  const int wr = wave >> 1, wc = wave & 1;
  const int quad = lane >> 4, l15 = lane & 15;

  const unsigned short* gsrc[4];
  unsigned short* ldst[4];
  #pragma unroll
  for(int p=0;p<4;p++){
    int ck  = ((p&1)<<8) + tid;            // 0..511
    int row = ck>>2, c = ck&3, pc = c ^ (row&3);
    if(p<2){ gsrc[p] = Xb + (size_t)(m0+row)*HID + (pc<<3); ldst[p] = &u.s.A[0][row][c<<3]; }
    else   { gsrc[p] = Wb + (size_t)(n0+row)*HID + (pc<<3); ldst[p] = &u.s.B[0][row][c<<3]; }
  }

  floatx4 acc[4][4];
  #pragma unroll
  for(int i=0;i<4;i++)
    #pragma unroll
    for(int j=0;j<4;j++) acc[i][j] = (floatx4){0.f,0.f,0.f,0.f};

  auto stage = [&](int buf, int k0){
    const int bo = buf*(128*32);
    #pragma unroll
    for(int p=0;p<4;p++) glds16(gsrc[p] + k0, ldst[p] + bo);
  };

  stage(0, 0);
  __syncthreads();

  const int swa = l15 & 3;
  for(int t=0;t<HID/32;t++){
    const int buf = t & 1;
    if(t < HID/32 - 1) stage(buf^1, (t+1)*32);
    short8 a[4], b[4];
    #pragma unroll
    for(int i=0;i<4;i++)
      a[i] = *reinterpret_cast<const short8*>(&u.s.A[buf][wr*64+i*16+l15][(quad^swa)<<3]);
    #pragma unroll
    for(int j=0;j<4;j++)
      b[j] = *reinterpret_cast<const short8*>(&u.s.B[buf][wc*64+j*16+l15][(quad^swa)<<3]);
    #pragma unroll
    for(int i=0;i<4;i++)
      #pragma unroll
      for(int j=0;j<4;j++)
        acc[i][j] = __builtin_amdgcn_mfma_f32_16x16x32_bf16(a[i], b[j], acc[i][j], 0, 0, 0);
    __syncthreads();
  }

  // ---- epilogue; C layout col=lane&15 (n), row=quad*4+reg (m) ----
  const int which = n0 / HID;
  const int nbase = n0 - which*HID + wc*64;
  const int head  = nbase >> 6;
  const int b_    = m0 >> 11;
  const int hb    = head*BATCH + b_;
  const int s0    = (m0 & 2047) + wr*64;
  if(which < 2){
    unsigned short* dst = which==0 ? Qb : Kb;
    const float* bias = which==0 ? bq : bk;
    const float scale = which==0 ? QSCALE : 1.0f;
    #pragma unroll
    for(int j=0;j<4;j++){
      const float bb = bias[nbase + j*16 + l15];
      #pragma unroll
      for(int i=0;i<4;i++)
        #pragma unroll
        for(int r=0;r<4;r++)
          u.T[wave][i*16 + quad*4 + r][j*16 + l15] = f2bf((acc[i][j][r] + bb)*scale);
    }
    #pragma unroll
    for(int p=0;p<8;p++){
      const int row = p*8 + (lane>>3), dc = (lane&7)*8;
      uint4 v = *reinterpret_cast<const uint4*>(&u.T[wave][row][dc]);
      *reinterpret_cast<uint4*>(dst + ((size_t)(hb<<11) + s0 + row)*HS + dc) = v;
    }
  } else {
    #pragma unroll
    for(int j=0;j<4;j++){
      const float bb = bv[nbase + j*16 + l15];
      #pragma unroll
      for(int i=0;i<4;i++){
        uint2 pk;
        pk.x = f2bf2(acc[i][j][0]+bb, acc[i][j][1]+bb);
        pk.y = f2bf2(acc[i][j][2]+bb, acc[i][j][3]+bb);
        *reinterpret_cast<uint2*>(&u.T[wave][j*16+l15][i*16 + quad*4]) = pk;  // T[d][m]
      }
    }
    #pragma unroll
    for(int p=0;p<8;p++){
      const int d = p*8 + (lane>>3), cm = lane & 7;
      uint4 v = *reinterpret_cast<const uint4*>(&u.T[wave][d][cm*8]);
      *reinterpret_cast<uint4*>(Vtb + ((size_t)(hb*HS) + d)*SEQ + s0 + cm*8) = v;
    }
  }
}

// ---------- flash attention: no-max softmax, S^T, K+V LDS double-buffered ----------
// grid HB*32; 64 q rows/block, 4 waves x 16 q rows. Coalesced async staging for
// BOTH K and V (V register-gather was TA-bound: 16 segments/load). Packed-P via
// stride-68 Ps (b64 ops, conflict-free).
__global__ __launch_bounds__(256) void attn_kernel(
    const unsigned short* __restrict__ Qb,   // [hb][2048][64] (pre-scaled, log2 domain)
    const unsigned short* __restrict__ Kb,   // [hb][2048][64]
    const unsigned short* __restrict__ Vtb,  // [hb][64][2048]
    const float* __restrict__ maskaddG,      // [B][2048]
    const int* __restrict__ flagsG,          // [B][32]
    float* __restrict__ out)                 // [B][2048][768]
{
  __shared__ __align__(16) unsigned short Ks2 [2][64][64];  // 16 KB
  __shared__ __align__(16) unsigned short Vts2[2][64][64];  // 16 KB
  __shared__ __align__(16) unsigned short Ps2 [4][16][68];  // 8.5 KB

  const int bid = blockIdx.x;
  const int hb = bid >> 5, qt = bid & 31, q0 = qt << 6;
  const int tid = threadIdx.x, wave = tid >> 6, lane = tid & 63;
  const int quad = lane >> 4, l15 = lane & 15;
  const int b_ = hb & 1, head = hb >> 1;

  // staging descriptors (chunk = p*256+tid; row=ck/8, c=ck%8, swizzle c^(row&7))
  const unsigned short* gK[2]; const unsigned short* gV[2];
  unsigned short* lK[2]; unsigned short* lV[2];
  #pragma unroll
  for(int p=0;p<2;p++){
    int ck = (p<<8) + tid;
    int row = ck>>3, c = ck&7, pc = c ^ (row&7);
    gK[p] = Kb  + ((size_t)(hb<<11) + row)*HS + (pc<<3);
    lK[p] = &Ks2[0][row][c<<3];
    gV[p] = Vtb + ((size_t)(hb*HS) + row)*SEQ + (pc<<3);
    lV[p] = &Vts2[0][row][c<<3];
  }
  auto stage = [&](int buf, int k0){
    const int bo = buf*(64*64);
    #pragma unroll
    for(int p=0;p<2;p++){
      glds16(gK[p] + (size_t)k0*HS, lK[p] + bo);
      glds16(gV[p] + k0,           lV[p] + bo);
    }
  };

  stage(0, 0);                               // async prefetch tile 0

  // Q fragments: direct b128 loads (scale folded in by GEMM)
  short8 a_q[2];
  {
    const unsigned short* qsrc = Qb + ((size_t)(hb<<11) + q0 + wave*16 + l15)*HS;
    a_q[0] = *reinterpret_cast<const short8*>(qsrc + quad*8);
    a_q[1] = *reinterpret_cast<const short8*>(qsrc + 32 + quad*8);
  }

  float lsum4[4] = {0.f,0.f,0.f,0.f};
  floatx4 o_acc[4];
  #pragma unroll
  for(int dt=0;dt<4;dt++) o_acc[dt] = (floatx4){0.f,0.f,0.f,0.f};

  __syncthreads();                           // tile 0 staged

  const int sw = l15 & 7;
  for(int t=0;t<SEQ/64;t++){
    const int buf = t & 1, k0 = t << 6;
    if(t < SEQ/64 - 1) stage(buf^1, k0 + 64);   // async prefetch next tile

    const unsigned short (*Kst)[64] = Ks2[buf];
    const unsigned short (*Vst)[64] = Vts2[buf];

    // S^T: rows = keys (quad*4+r), cols = queries (l15)
    floatx4 st[4];
    #pragma unroll
    for(int kt=0;kt<4;kt++){
      st[kt] = (floatx4){0.f,0.f,0.f,0.f};
      #pragma unroll
      for(int c=0;c<2;c++){
        short8 kf = *reinterpret_cast<const short8*>(
            &Kst[kt*16 + l15][(((c<<2)+quad)^sw)<<3]);
        st[kt] = __builtin_amdgcn_mfma_f32_16x16x32_bf16(kf, a_q[c], st[kt], 0, 0, 0);
      }
    }

    // P = exp2(S [+ mask]); pack pairs; write P[q=l15][key] (2x b64)
    const bool masked = (flagsG[(b_<<5) + t] != 0);   // wave-uniform
    #pragma unroll
    for(int kt=0;kt<4;kt++){
      float p0,p1,p2,p3;
      if(!masked){
        p0 = exp2f(st[kt][0]); p1 = exp2f(st[kt][1]);
        p2 = exp2f(st[kt][2]); p3 = exp2f(st[kt][3]);
      } else {
        float4 ma = *reinterpret_cast<const float4*>(
            maskaddG + (b_<<11) + k0 + kt*16 + quad*4);
        p0 = exp2f(st[kt][0] + ma.x); p1 = exp2f(st[kt][1] + ma.y);
        p2 = exp2f(st[kt][2] + ma.z); p3 = exp2f(st[kt][3] + ma.w);
      }
      lsum4[0] += p0; lsum4[1] += p1; lsum4[2] += p2; lsum4[3] += p3;
      uint2 pk;
      pk.x = f2bf2(p0, p1);
      pk.y = f2bf2(p2, p3);
      *reinterpret_cast<uint2*>(&Ps2[wave][l15][kt*16 + quad*4]) = pk;
    }

    // A-frag read (same-wave RAW via lgkmcnt), then O += P V
    short8 ap0, ap1;
    {
      unsigned long long x0 = *reinterpret_cast<const unsigned long long*>(&Ps2[wave][l15][quad*8]);
      unsigned long long x1 = *reinterpret_cast<const unsigned long long*>(&Ps2[wave][l15][quad*8 + 4]);
      unsigned long long y0 = *reinterpret_cast<const unsigned long long*>(&Ps2[wave][l15][32 + quad*8]);
      unsigned long long y1 = *reinterpret_cast<const unsigned long long*>(&Ps2[wave][l15][32 + quad*8 + 4]);
      union { unsigned long long u[2]; short8 s; } cv0, cv1;
      cv0.u[0] = x0; cv0.u[1] = x1;
      cv1.u[0] = y0; cv1.u[1] = y1;
      ap0 = cv0.s; ap1 = cv1.s;
    }
    #pragma unroll
    for(int dt=0;dt<4;dt++){
      short8 bv0 = *reinterpret_cast<const short8*>(&Vst[dt*16 + l15][(quad^sw)<<3]);
      short8 bv1 = *reinterpret_cast<const short8*>(&Vst[dt*16 + l15][((4+quad)^sw)<<3]);
      o_acc[dt] = __builtin_amdgcn_mfma_f32_16x16x32_bf16(ap0, bv0, o_acc[dt], 0, 0, 0);
      o_acc[dt] = __builtin_amdgcn_mfma_f32_16x16x32_bf16(ap1, bv1, o_acc[dt], 0, 0, 0);
    }
    __syncthreads();   // staged t+1 drained; everyone done reading buf
  }

  // per-query row sum: lane holds q=l15 partial; reduce across quads, redistribute
  float lsum = (lsum4[0]+lsum4[1]) + (lsum4[2]+lsum4[3]);
  lsum += __shfl_xor(lsum, 16);
  lsum += __shfl_xor(lsum, 32);
  float linv[4];
  #pragma unroll
  for(int r=0;r<4;r++) linv[r] = 1.0f / __shfl(lsum, quad*4 + r);

  #pragma unroll
  for(int dt=0;dt<4;dt++){
    #pragma unroll
    for(int r=0;r<4;r++){
      const int srow = q0 + wave*16 + quad*4 + r;
      out[((size_t)(b_<<11) + srow)*HID + (head<<6) + dt*16 + l15] =
        o_acc[dt][r] * linv[r];
    }
  }
}

extern "C" void kernel_launch(void* const* d_in, const int* in_sizes, int n_in,
                              void* d_out, int out_size, void* d_ws, size_t ws_size,
                              hipStream_t stream) {
  const float* X    = (const float*)d_in[0];
  const int*   mask = (const int*)  d_in[1];
  const float* Wq   = (const float*)d_in[2];
  const float* bq   = (const float*)d_in[3];
  const float* Wk   = (const float*)d_in[4];
  const float* bk   = (const float*)d_in[5];
  const float* Wv   = (const float*)d_in[6];
  const float* bv   = (const float*)d_in[7];
  float* out = (float*)d_out;

  char* ws = (char*)d_ws;
  unsigned short* Xb  = (unsigned short*)ws;
  unsigned short* Wb  = Xb  + (size_t)MROWS*HID;
  unsigned short* Qb  = Wb  + (size_t)N3*HID;
  unsigned short* Kb  = Qb  + (size_t)HB*SEQ*HS;
  unsigned short* Vtb = Kb  + (size_t)HB*SEQ*HS;
  float* maskaddG = (float*)(Vtb + (size_t)HB*SEQ*HS);
  int*   flagsG   = (int*)(maskaddG + MROWS);

  const int total_quads = (MROWS*HID + 3*HID*HID)/4;
  f2bf_all_kernel<<<total_quads/256 + 1, 256, 0, stream>>>(
      X, Wq, Wk, Wv, mask, Xb, Wb, maskaddG, flagsG);

  qkv_gemm_kernel<<<dim3(N3/128, MROWS/128), 256, 0, stream>>>(
      Xb, Wb, bq, bk, bv, Qb, Kb, Vtb);

  attn_kernel<<<HB*32, 256, 0, stream>>>(
      Qb, Kb, Vtb, maskaddG, flagsG, out);
}